// Round 19
// baseline (209.124 us; speedup 1.0000x reference)
//
#include <hip/hip_runtime.h>

#define B_   32
#define C_   64
#define T_   300
#define J_   25
#define K9   9
constexpr int PLANE = T_ * J_;           // 7500
constexpr int BCTJ  = B_ * C_ * PLANE;   // 15,360,000
constexpr float BN_EPS = 1e-5f;
constexpr float BN_N   = (float)(B_ * T_ * J_);  // 240000

typedef __attribute__((ext_vector_type(8))) _Float16 f16x8;
typedef __attribute__((ext_vector_type(2))) _Float16 f16x2;
typedef __attribute__((ext_vector_type(4))) float f32x4;
typedef __attribute__((ext_vector_type(8))) unsigned short u16x8;
typedef __attribute__((ext_vector_type(4))) unsigned short u16x4;

__device__ inline unsigned short f2h(float f) {
  _Float16 h = (_Float16)f;
  return __builtin_bit_cast(unsigned short, h);
}
__device__ inline float h2f(unsigned short u) {
  return (float)__builtin_bit_cast(_Float16, u);
}

// async global->LDS, 16B per lane; lds dest must be wave-uniform base (+lane*16)
__device__ inline void gload16(const unsigned short* g, unsigned short* l) {
  __builtin_amdgcn_global_load_lds(
      (const __attribute__((address_space(1))) unsigned int*)g,
      (__attribute__((address_space(3))) unsigned int*)l, 16, 0, 0);
}

// ---------------------------------------------------------------------------
// K0: weight prep (fp16).
__global__ __launch_bounds__(256) void prep_kernel(const float* __restrict__ tw,
                                                   const float* __restrict__ gw,
                                                   const float* __restrict__ A,
                                                   unsigned short* __restrict__ Wb,
                                                   unsigned short* __restrict__ Gb,
                                                   unsigned short* __restrict__ AdT) {
  int idx = blockIdx.x * 256 + threadIdx.x;
  if (idx < C_ * C_ * K9) {
    int o = idx / (C_ * K9);
    int rem = idx % (C_ * K9);
    int c = rem / K9, kt = rem % K9;
    Wb[kt * (C_ * C_) + o * C_ + c] = f2h(tw[idx]);
  } else if (idx < C_ * C_ * K9 + C_ * C_) {
    int i = idx - C_ * C_ * K9;
    Gb[i] = f2h(gw[i]);
  } else if (idx < C_ * C_ * K9 + C_ * C_ + 256 * 256) {
    int i = idx - (C_ * C_ * K9 + C_ * C_);
    int n = i >> 8, m = i & 255;
    float v = 0.f;
    if (n < 250 && m < 250) {
      if (n / 25 == m / 25) v = A[(m % 25) * 25 + (n % 25)];
    }
    AdT[i] = f2h(v);
  }
}

// ---------------------------------------------------------------------------
// K1: GCN (fp16). 256 thr, 4 blocks/CU, aliased 32KB LDS, fused BN1 partials.
constexpr int TTG = 10;
__global__ __launch_bounds__(256, 4) void gcn_mfma_kernel(
    const float* __restrict__ x, const unsigned short* __restrict__ AdT,
    const unsigned short* __restrict__ Gb, const float* __restrict__ gbias,
    unsigned short* __restrict__ y1Tb, float* __restrict__ part1) {
  __shared__ unsigned short Xs[C_ * 256];     // 32 KB, triple-aliased
  __shared__ float sred[4][64], qred[4][64];  // 2 KB
  int bid = (blockIdx.x & 7) * 120 + (blockIdx.x >> 3);   // 960 = 8*120
  int b = bid / (T_ / TTG), tile = bid % (T_ / TTG);
  int t0 = tile * TTG;
  int tid = threadIdx.x;

  {
    size_t sbase = (size_t)b * (C_ * PLANE) + (size_t)t0 * J_;
    int c0 = tid >> 6;
    int m  = (tid & 63) * 4;
    float4 vb[16];
#pragma unroll
    for (int k = 0; k < 16; ++k) {
      size_t off = sbase + (size_t)(c0 + 4 * k) * PLANE + m;
      size_t offc = off > (size_t)(BCTJ - 4) ? (size_t)(BCTJ - 4) : off;
      float4 v = *(const float4*)(x + offc);
      if (off != offc) {           // clamped-by-2 edge: shift to real elements
        v.x = v.z; v.y = v.w; v.z = 0.f; v.w = 0.f;
      }
      vb[k] = v;
    }
#pragma unroll
    for (int k = 0; k < 16; ++k) {
      int c = c0 + 4 * k;
      unsigned p0 = (unsigned)f2h(vb[k].x) | ((unsigned)f2h(vb[k].y) << 16);
      unsigned p1 = (unsigned)f2h(vb[k].z) | ((unsigned)f2h(vb[k].w) << 16);
      int elem = ((c << 8) | m) ^ ((c & 7) << 3);
      *(uint2*)&Xs[elem] = make_uint2(p0, p1);
    }
  }
  __syncthreads();

  int l = tid & 63, w = tid >> 6;
  int lr = l & 15, lh = l >> 4;
  int n0 = w * 64;

  // ---- pass 1: XA = X * Ad ----
  f32x4 acc1[4][4];
#pragma unroll
  for (int mf = 0; mf < 4; ++mf)
#pragma unroll
    for (int nf = 0; nf < 4; ++nf) acc1[mf][nf] = (f32x4)0.f;

  int qminw = ((n0 / 25) * 25) >> 5;
  int qmaxw = min(7, ((((n0 + 63) / 25) + 1) * 25 - 1) >> 5);
  for (int q = qminw; q <= qmaxw; ++q) {
    f16x8 afx[4];
#pragma unroll
    for (int mf = 0; mf < 4; ++mf) {
      int c = mf * 16 + lr;
      int elem = ((c << 8) | (q * 32 + lh * 8)) ^ ((c & 7) << 3);
      afx[mf] = *(const f16x8*)&Xs[elem];
    }
#pragma unroll
    for (int nf = 0; nf < 4; ++nf) {
      int nbase = n0 + nf * 16;
      int ql = ((nbase / 25) * 25) >> 5;
      int qh = min(7, ((((nbase + 15) / 25) + 1) * 25 - 1) >> 5);
      if (q < ql || q > qh) continue;
      int n = nbase + lr;
      f16x8 bfx = *(const f16x8*)&AdT[n * 256 + q * 32 + lh * 8];
#pragma unroll
      for (int mf = 0; mf < 4; ++mf)
        acc1[mf][nf] = __builtin_amdgcn_mfma_f32_16x16x32_f16(afx[mf], bfx, acc1[mf][nf], 0, 0, 0);
    }
  }
  __syncthreads();

  // ---- write XA into same buffer, [n][c] swizzled ----
#pragma unroll
  for (int mf = 0; mf < 4; ++mf) {
    int cb = mf * 16 + 4 * lh;
#pragma unroll
    for (int nf = 0; nf < 4; ++nf) {
      int n = n0 + nf * 16 + lr;
      unsigned p0 = (unsigned)f2h(acc1[mf][nf][0]) | ((unsigned)f2h(acc1[mf][nf][1]) << 16);
      unsigned p1 = (unsigned)f2h(acc1[mf][nf][2]) | ((unsigned)f2h(acc1[mf][nf][3]) << 16);
      int e0 = ((n << 6) | cb) ^ ((n & 7) << 3);
      *(uint2*)&Xs[e0] = make_uint2(p0, p1);
    }
  }
  __syncthreads();

  // ---- pass 2: y1 = Gb * XA + bias ----
  f32x4 acc[4][4];
#pragma unroll
  for (int mf = 0; mf < 4; ++mf)
#pragma unroll
    for (int nf = 0; nf < 4; ++nf) acc[mf][nf] = (f32x4)0.f;

  f16x8 af[4][2];
#pragma unroll
  for (int mf = 0; mf < 4; ++mf) {
    const unsigned short* wp = Gb + (mf * 16 + lr) * C_ + lh * 8;
    af[mf][0] = *(const f16x8*)(wp);
    af[mf][1] = *(const f16x8*)(wp + 32);
  }
  f16x8 bfr[4][2];
#pragma unroll
  for (int nf = 0; nf < 4; ++nf) {
    int r = n0 + nf * 16 + lr;
    int sw = (r & 7) << 3;
    bfr[nf][0] = *(const f16x8*)&Xs[((r << 6) | (lh * 8)) ^ sw];
    bfr[nf][1] = *(const f16x8*)&Xs[((r << 6) | (32 + lh * 8)) ^ sw];
  }
#pragma unroll
  for (int mf = 0; mf < 4; ++mf)
#pragma unroll
    for (int nf = 0; nf < 4; ++nf) {
      acc[mf][nf] = __builtin_amdgcn_mfma_f32_16x16x32_f16(af[mf][0], bfr[nf][0], acc[mf][nf], 0, 0, 0);
      acc[mf][nf] = __builtin_amdgcn_mfma_f32_16x16x32_f16(af[mf][1], bfr[nf][1], acc[mf][nf], 0, 0, 0);
    }
  __syncthreads();

  // ---- epilogue: stats + f16 transpose into LDS [n][c] ----
#pragma unroll
  for (int mf = 0; mf < 4; ++mf) {
    float4 gb4 = *(const float4*)(gbias + mf * 16 + 4 * lh);
    int cb = mf * 16 + 4 * lh;
    float sv[4] = {0.f, 0.f, 0.f, 0.f}, qv[4] = {0.f, 0.f, 0.f, 0.f};
#pragma unroll
    for (int nf = 0; nf < 4; ++nf) {
      int n = n0 + nf * 16 + lr;
      float v0 = acc[mf][nf][0] + gb4.x;
      float v1 = acc[mf][nf][1] + gb4.y;
      float v2 = acc[mf][nf][2] + gb4.z;
      float v3 = acc[mf][nf][3] + gb4.w;
      if (n < 250) {
        sv[0] += v0; qv[0] += v0 * v0;
        sv[1] += v1; qv[1] += v1 * v1;
        sv[2] += v2; qv[2] += v2 * v2;
        sv[3] += v3; qv[3] += v3 * v3;
      }
      unsigned p0 = (unsigned)f2h(v0) | ((unsigned)f2h(v1) << 16);
      unsigned p1 = (unsigned)f2h(v2) | ((unsigned)f2h(v3) << 16);
      int e0 = ((n << 6) | cb) ^ ((n & 7) << 3);
      *(uint2*)&Xs[e0] = make_uint2(p0, p1);
    }
#pragma unroll
    for (int reg = 0; reg < 4; ++reg) {
      float s = sv[reg], q = qv[reg];
#pragma unroll
      for (int m = 1; m < 16; m <<= 1) {
        s += __shfl_xor(s, m);
        q += __shfl_xor(q, m);
      }
      if (lr == 0) {
        int o = mf * 16 + 4 * lh + reg;
        sred[w][o] = s; qred[w][o] = q;
      }
    }
  }
  __syncthreads();

  unsigned short* ydst = y1Tb + ((size_t)b * PLANE + (size_t)t0 * J_) * C_;
#pragma unroll
  for (int it = 0; it < 8; ++it) {
    int task = it * 256 + tid;
    int n = task >> 3, ch = task & 7;
    if (n < 250) {
      int e = ((n << 6) | (ch * 8)) ^ ((n & 7) << 3);
      u16x8 v = *(const u16x8*)&Xs[e];
      *(u16x8*)(ydst + (size_t)n * C_ + ch * 8) = v;
    }
  }
  if (tid < 64) {
    float S = 0.f, Q = 0.f;
#pragma unroll
    for (int i = 0; i < 4; ++i) { S += sred[i][tid]; Q += qred[i][tid]; }
    part1[bid * 128 + tid] = S;
    part1[bid * 128 + 64 + tid] = Q;
  }
}

// ---------------------------------------------------------------------------
// K3: grid-parallel reduce: one block per channel c (grid=64).
__global__ __launch_bounds__(256) void bnparam_reduce_kernel(
    const float* __restrict__ part, int nparts,
    const float* __restrict__ g, const float* __restrict__ b,
    float* __restrict__ bnp, unsigned short* __restrict__ bnph) {
  int c = blockIdx.x;
  int tid = threadIdx.x;
  float S = 0.f, Q = 0.f;
  for (int k = tid; k < nparts; k += 256) {
    S += part[k * 128 + c];
    Q += part[k * 128 + 64 + c];
  }
#pragma unroll
  for (int off = 32; off > 0; off >>= 1) {
    S += __shfl_down(S, off);
    Q += __shfl_down(Q, off);
  }
  __shared__ float ls[2][4];
  int wv = tid >> 6, ln = tid & 63;
  if (ln == 0) { ls[0][wv] = S; ls[1][wv] = Q; }
  __syncthreads();
  if (tid == 0) {
    float St = ls[0][0] + ls[0][1] + ls[0][2] + ls[0][3];
    float Qt = ls[1][0] + ls[1][1] + ls[1][2] + ls[1][3];
    float mean = St / BN_N;
    float var = Qt / BN_N - mean * mean;
    float inv = rsqrtf(var + BN_EPS);
    float sc = g[c] * inv;
    float sh = b[c] - mean * sc;
    bnp[c] = sc;
    bnp[C_ + c] = sh;
    bnph[c] = f2h(sc);
    bnph[C_ + c] = f2h(sh);
  }
}

// ---------------------------------------------------------------------------
// K4: TCN, (b,j) halo-free blocks. zs[312][64] staging (DMA, pre-swizzled src),
//     BN1+ReLU fused at B-frag read; output via LDS [t][72] transpose ->
//     full 128B y2T row stores. 3 blocks/CU.
constexpr int ZRJ = 312;                     // 4 + 300 + 8 rows (t' = r-4)
__global__ __launch_bounds__(256, 3) void tcn_mfma_kernel(
    const unsigned short* __restrict__ y1Tb, const unsigned short* __restrict__ Wb,
    const unsigned short* __restrict__ bnph1, const float* __restrict__ tbias,
    unsigned short* __restrict__ y2T, float* __restrict__ part2) {
  __shared__ __align__(16) unsigned short zsU[304 * 72];   // 43776 B (>= 312*64*2)
  __shared__ float sred[4][64], qred[4][64];               // 2 KB
  unsigned short* zs  = zsU;                 // [312][64] staging view
  unsigned short* zs2 = zsU;                 // [304][72] transpose view
  int bid = (blockIdx.x & 7) * 100 + (blockIdx.x >> 3);    // 800 = 8*100
  int b = bid / J_, j = bid % J_;
  int tid = threadIdx.x;

  // ---- phase 1: DMA 312 rows x 128B; row r <- y1T[b][clamp(r-4)*25+j] ----
  {
    const unsigned short* bb = y1Tb + (size_t)b * PLANE * C_;
#pragma unroll
    for (int k = 0; k < 10; ++k) {
      int P = k * 256 + tid;
      if (P < ZRJ * 8) {
        int r = P >> 3, p = P & 7;
        int tc = min(max(r - 4, 0), T_ - 1);
        const unsigned short* src = bb + (size_t)(tc * J_ + j) * C_ + ((p ^ (r & 7)) << 3);
        int ldsoff = (k * 256 + (tid & 192)) << 4;   // wave-uniform byte base
        gload16(src, (unsigned short*)((char*)zs + ldsoff));
      }
    }
  }

  int l = tid & 63, w = tid >> 6;
  int lr = l & 15, lh = l >> 4;
  int n0 = w * 80;                         // wave3: 240
  int nfmax = (w < 3) ? 5 : 4;             // 3*80 + 64 = 304 output slots

  // per-lane BN params for c-octets [lh*8, +8) and [32+lh*8, +8)
  f16x2 scA[4], shA[4], scB[4], shB[4];
  {
    const f16x2* scp = (const f16x2*)(bnph1);
    const f16x2* shp = (const f16x2*)(bnph1 + C_);
#pragma unroll
    for (int i = 0; i < 4; ++i) {
      scA[i] = scp[lh * 4 + i];      shA[i] = shp[lh * 4 + i];
      scB[i] = scp[16 + lh * 4 + i]; shB[i] = shp[16 + lh * 4 + i];
    }
  }
  f16x2 z2 = (f16x2)((_Float16)0.f);

  f32x4 acc[4][5];
#pragma unroll
  for (int mf = 0; mf < 4; ++mf)
#pragma unroll
    for (int nf = 0; nf < 5; ++nf) acc[mf][nf] = (f32x4)0.f;

  // weight prefetch for kt=0 (overlaps DMA drain)
  f16x8 afc[4][2];
#pragma unroll
  for (int mf = 0; mf < 4; ++mf) {
    const unsigned short* wp = Wb + (mf * 16 + lr) * C_ + lh * 8;
    afc[mf][0] = *(const f16x8*)(wp);
    afc[mf][1] = *(const f16x8*)(wp + 32);
  }
  __syncthreads();   // drains DMA vmcnt before LDS reads

#pragma unroll
  for (int kt = 0; kt < K9; ++kt) {
    f16x8 afn[4][2];
    if (kt < K9 - 1) {
#pragma unroll
      for (int mf = 0; mf < 4; ++mf) {
        const unsigned short* wp = Wb + (kt + 1) * (C_ * C_) + (mf * 16 + lr) * C_ + lh * 8;
        afn[mf][0] = *(const f16x8*)(wp);
        afn[mf][1] = *(const f16x8*)(wp + 32);
      }
    }
    f16x8 bfr[5][2];
#pragma unroll
    for (int nf = 0; nf < 5; ++nf) {
      if (nf >= nfmax) continue;
      int r = n0 + nf * 16 + lr + kt;      // staged row; t' = r-4
      int sw = (r & 7) << 3;
      uint4 ra = *(const uint4*)&zs[((r << 6) | (lh * 8)) ^ sw];
      uint4 rb = *(const uint4*)&zs[((r << 6) | (32 + lh * 8)) ^ sw];
      f16x2 a0 = __builtin_bit_cast(f16x2, ra.x);
      f16x2 a1 = __builtin_bit_cast(f16x2, ra.y);
      f16x2 a2 = __builtin_bit_cast(f16x2, ra.z);
      f16x2 a3 = __builtin_bit_cast(f16x2, ra.w);
      f16x2 b0 = __builtin_bit_cast(f16x2, rb.x);
      f16x2 b1 = __builtin_bit_cast(f16x2, rb.y);
      f16x2 b2 = __builtin_bit_cast(f16x2, rb.z);
      f16x2 b3 = __builtin_bit_cast(f16x2, rb.w);
      a0 = __builtin_elementwise_max(a0 * scA[0] + shA[0], z2);
      a1 = __builtin_elementwise_max(a1 * scA[1] + shA[1], z2);
      a2 = __builtin_elementwise_max(a2 * scA[2] + shA[2], z2);
      a3 = __builtin_elementwise_max(a3 * scA[3] + shA[3], z2);
      b0 = __builtin_elementwise_max(b0 * scB[0] + shB[0], z2);
      b1 = __builtin_elementwise_max(b1 * scB[1] + shB[1], z2);
      b2 = __builtin_elementwise_max(b2 * scB[2] + shB[2], z2);
      b3 = __builtin_elementwise_max(b3 * scB[3] + shB[3], z2);
      unsigned m = ((unsigned)(r - 4) < (unsigned)T_) ? 0xFFFFFFFFu : 0u;
      uint4 pa, pb;
      pa.x = __builtin_bit_cast(unsigned int, a0) & m;
      pa.y = __builtin_bit_cast(unsigned int, a1) & m;
      pa.z = __builtin_bit_cast(unsigned int, a2) & m;
      pa.w = __builtin_bit_cast(unsigned int, a3) & m;
      pb.x = __builtin_bit_cast(unsigned int, b0) & m;
      pb.y = __builtin_bit_cast(unsigned int, b1) & m;
      pb.z = __builtin_bit_cast(unsigned int, b2) & m;
      pb.w = __builtin_bit_cast(unsigned int, b3) & m;
      bfr[nf][0] = __builtin_bit_cast(f16x8, pa);
      bfr[nf][1] = __builtin_bit_cast(f16x8, pb);
    }
    __builtin_amdgcn_s_setprio(1);
#pragma unroll
    for (int mf = 0; mf < 4; ++mf)
#pragma unroll
      for (int nf = 0; nf < 5; ++nf) {
        if (nf >= nfmax) continue;
        acc[mf][nf] = __builtin_amdgcn_mfma_f32_16x16x32_f16(afc[mf][0], bfr[nf][0], acc[mf][nf], 0, 0, 0);
        acc[mf][nf] = __builtin_amdgcn_mfma_f32_16x16x32_f16(afc[mf][1], bfr[nf][1], acc[mf][nf], 0, 0, 0);
      }
    __builtin_amdgcn_s_setprio(0);
    if (kt < K9 - 1) {
#pragma unroll
      for (int mf = 0; mf < 4; ++mf) {
        afc[mf][0] = afn[mf][0];
        afc[mf][1] = afn[mf][1];
      }
    }
  }
  __syncthreads();   // done reading zs before zs2 overwrite

  // ---- epilogue: stats + f16 transpose into LDS [t][72] ----
#pragma unroll
  for (int mf = 0; mf < 4; ++mf) {
    float4 tb4 = *(const float4*)(tbias + mf * 16 + 4 * lh);
    float sv[4] = {0.f, 0.f, 0.f, 0.f}, qv[4] = {0.f, 0.f, 0.f, 0.f};
#pragma unroll
    for (int nf = 0; nf < 5; ++nf) {
      if (nf >= nfmax) continue;
      int t = n0 + nf * 16 + lr;
      if (t < T_) {
        float v0 = acc[mf][nf][0] + tb4.x;
        float v1 = acc[mf][nf][1] + tb4.y;
        float v2 = acc[mf][nf][2] + tb4.z;
        float v3 = acc[mf][nf][3] + tb4.w;
        sv[0] += v0; qv[0] += v0 * v0;
        sv[1] += v1; qv[1] += v1 * v1;
        sv[2] += v2; qv[2] += v2 * v2;
        sv[3] += v3; qv[3] += v3 * v3;
        unsigned p0 = (unsigned)f2h(v0) | ((unsigned)f2h(v1) << 16);
        unsigned p1 = (unsigned)f2h(v2) | ((unsigned)f2h(v3) << 16);
        *(uint2*)&zs2[t * 72 + mf * 16 + 4 * lh] = make_uint2(p0, p1);
      }
    }
#pragma unroll
    for (int reg = 0; reg < 4; ++reg) {
      float s = sv[reg], q = qv[reg];
#pragma unroll
      for (int m = 1; m < 16; m <<= 1) {
        s += __shfl_xor(s, m);
        q += __shfl_xor(q, m);
      }
      if (lr == 0) {
        int o = mf * 16 + 4 * lh + reg;
        sred[w][o] = s; qred[w][o] = q;
      }
    }
  }
  __syncthreads();

  // ---- store: full 128B y2T rows (8 lanes x 16B per row) ----
  unsigned short* ydst = y2T + ((size_t)b * PLANE + j) * C_;
#pragma unroll
  for (int it = 0; it < 10; ++it) {
    int task = it * 256 + tid;
    if (task < T_ * 8) {
      int t = task >> 3, ch = task & 7;
      u16x8 v = *(const u16x8*)&zs2[t * 72 + ch * 8];
      *(u16x8*)(ydst + (size_t)t * (J_ * C_) + ch * 8) = v;
    }
  }
  if (tid < 64) {
    float S = 0.f, Q = 0.f;
#pragma unroll
    for (int i = 0; i < 4; ++i) { S += sred[i][tid]; Q += qred[i][tid]; }
    part2[bid * 128 + tid] = S;
    part2[bid * 128 + 64 + tid] = Q;
  }
}

// ---------------------------------------------------------------------------
// K5: out = relu(bn2(y2T) + x). 64-row LDS-transpose tile; XCD-matched swizzle.
constexpr int FR = 64;
constexpr int NCH = (PLANE + FR - 1) / FR;   // 118
__global__ __launch_bounds__(256) void final_kernel(
    const unsigned short* __restrict__ y2T, const float* __restrict__ x,
    const float* __restrict__ bnp2, float* __restrict__ out) {
  __shared__ float zt[FR][65];   // 16.6 KB
  int lb = (blockIdx.x & 7) * (B_ * NCH / 8) + (blockIdx.x >> 3);  // 3776 = 8*472
  int b = lb / NCH, ch = lb % NCH;
  int r0 = ch * FR;
  int rem = min(FR, PLANE - r0);   // 64 or 12
  int tid = threadIdx.x;
  {
    int c8 = (tid & 7) * 8;
    const unsigned short* src = y2T + ((size_t)b * PLANE + r0) * C_ + c8;
#pragma unroll
    for (int k = 0; k < 2; ++k) {
      int r = (tid >> 3) + k * 32;
      if (r < rem) {
        u16x8 v = *(const u16x8*)(src + (size_t)r * C_);
#pragma unroll
        for (int i = 0; i < 8; ++i) zt[r][c8 + i] = h2f(v[i]);
      }
    }
  }
  __syncthreads();
  int pos = (tid & 31) * 2;
  int cs = tid >> 5;
#pragma unroll
  for (int pass = 0; pass < 8; ++pass) {
    int c = pass * 8 + cs;
    if (pos < rem) {
      float sc = bnp2[c], sh = bnp2[C_ + c];
      size_t gi = (size_t)(b * C_ + c) * PLANE + r0 + pos;
      float z0 = zt[pos][c], z1 = zt[pos + 1][c];
      float2 xv = *(const float2*)(x + gi);
      float2 o2;
      o2.x = fmaxf(fmaf(z0, sc, sh) + xv.x, 0.f);
      o2.y = fmaxf(fmaf(z1, sc, sh) + xv.y, 0.f);
      *(float2*)(out + gi) = o2;
    }
  }
}

// ---------------------------------------------------------------------------
extern "C" void kernel_launch(void* const* d_in, const int* in_sizes, int n_in,
                              void* d_out, int out_size, void* d_ws, size_t ws_size,
                              hipStream_t stream) {
  const float* x     = (const float*)d_in[0];
  const float* A     = (const float*)d_in[1];
  const float* gcn_w = (const float*)d_in[2];
  const float* gcn_b = (const float*)d_in[3];
  const float* bn1_g = (const float*)d_in[4];
  const float* bn1_b = (const float*)d_in[5];
  const float* tcn_w = (const float*)d_in[6];
  const float* tcn_b = (const float*)d_in[7];
  const float* bn2_g = (const float*)d_in[8];
  const float* bn2_b = (const float*)d_in[9];
  float* out = (float*)d_out;

  unsigned short* y1Tb = (unsigned short*)d_ws;           // BCTJ f16
  unsigned short* y2T  = y1Tb + BCTJ;                     // BCTJ f16
  unsigned short* Wb   = y2T + BCTJ;                      // 36,864 f16
  unsigned short* Gb   = Wb + C_ * C_ * K9;               // 4,096 f16
  unsigned short* AdT  = Gb + C_ * C_;                    // 65,536 f16
  unsigned short* bnph = AdT + 256 * 256;                 // 256 f16 (bn1h, bn2h)
  float* part = (float*)(bnph + 256);                     // 960*128 f32
  float* bnp  = part + 960 * 128;                         // 256 f32

  int prep_n = C_ * C_ * K9 + C_ * C_ + 256 * 256;
  prep_kernel<<<(prep_n + 255) / 256, 256, 0, stream>>>(tcn_w, gcn_w, A, Wb, Gb, AdT);
  gcn_mfma_kernel<<<B_ * (T_ / TTG), 256, 0, stream>>>(x, AdT, Gb, gcn_b, y1Tb, part);
  bnparam_reduce_kernel<<<64, 256, 0, stream>>>(part, B_ * (T_ / TTG), bn1_g, bn1_b, bnp, bnph);
  tcn_mfma_kernel<<<B_ * J_, 256, 0, stream>>>(y1Tb, Wb, bnph, tcn_b, y2T, part);
  bnparam_reduce_kernel<<<64, 256, 0, stream>>>(part, B_ * J_, bn2_g, bn2_b, bnp + 128, bnph + 128);
  final_kernel<<<B_ * NCH, 256, 0, stream>>>(y2T, x, bnp + 128, out);
}

// Round 20
// 118.172 us; speedup vs baseline: 1.7696x; 1.7696x over previous
//
#include <hip/hip_runtime.h>

#define B_   32
#define C_   64
#define T_   300
#define J_   25
#define K9   9
constexpr int PLANE = T_ * J_;           // 7500
constexpr int BCTJ  = B_ * C_ * PLANE;   // 15,360,000
constexpr float BN_EPS = 1e-5f;
constexpr float BN_N   = (float)(B_ * T_ * J_);  // 240000

typedef __attribute__((ext_vector_type(8))) _Float16 f16x8;
typedef __attribute__((ext_vector_type(2))) _Float16 f16x2;
typedef __attribute__((ext_vector_type(4))) float f32x4;
typedef __attribute__((ext_vector_type(8))) unsigned short u16x8;
typedef __attribute__((ext_vector_type(4))) unsigned short u16x4;

__device__ inline unsigned short f2h(float f) {
  _Float16 h = (_Float16)f;
  return __builtin_bit_cast(unsigned short, h);
}
__device__ inline float h2f(unsigned short u) {
  return (float)__builtin_bit_cast(_Float16, u);
}

// async global->LDS, 16B per lane; lds dest must be wave-uniform base (+lane*16)
__device__ inline void gload16(const unsigned short* g, unsigned short* l) {
  __builtin_amdgcn_global_load_lds(
      (const __attribute__((address_space(1))) unsigned int*)g,
      (__attribute__((address_space(3))) unsigned int*)l, 16, 0, 0);
}

// ---------------------------------------------------------------------------
// K0: weight prep (fp16).
__global__ __launch_bounds__(256) void prep_kernel(const float* __restrict__ tw,
                                                   const float* __restrict__ gw,
                                                   const float* __restrict__ A,
                                                   unsigned short* __restrict__ Wb,
                                                   unsigned short* __restrict__ Gb,
                                                   unsigned short* __restrict__ AdT) {
  int idx = blockIdx.x * 256 + threadIdx.x;
  if (idx < C_ * C_ * K9) {
    int o = idx / (C_ * K9);
    int rem = idx % (C_ * K9);
    int c = rem / K9, kt = rem % K9;
    Wb[kt * (C_ * C_) + o * C_ + c] = f2h(tw[idx]);
  } else if (idx < C_ * C_ * K9 + C_ * C_) {
    int i = idx - C_ * C_ * K9;
    Gb[i] = f2h(gw[i]);
  } else if (idx < C_ * C_ * K9 + C_ * C_ + 256 * 256) {
    int i = idx - (C_ * C_ * K9 + C_ * C_);
    int n = i >> 8, m = i & 255;
    float v = 0.f;
    if (n < 250 && m < 250) {
      if (n / 25 == m / 25) v = A[(m % 25) * 25 + (n % 25)];
    }
    AdT[i] = f2h(v);
  }
}

// ---------------------------------------------------------------------------
// K1: GCN (fp16). 256 thr, 4 blocks/CU, aliased 32KB LDS, fused BN1 partials.
constexpr int TTG = 10;
__global__ __launch_bounds__(256, 4) void gcn_mfma_kernel(
    const float* __restrict__ x, const unsigned short* __restrict__ AdT,
    const unsigned short* __restrict__ Gb, const float* __restrict__ gbias,
    unsigned short* __restrict__ y1Tb, float* __restrict__ part1) {
  __shared__ unsigned short Xs[C_ * 256];     // 32 KB, triple-aliased
  __shared__ float sred[4][64], qred[4][64];  // 2 KB
  int bid = (blockIdx.x & 7) * 120 + (blockIdx.x >> 3);   // 960 = 8*120
  int b = bid / (T_ / TTG), tile = bid % (T_ / TTG);
  int t0 = tile * TTG;
  int tid = threadIdx.x;

  {
    size_t sbase = (size_t)b * (C_ * PLANE) + (size_t)t0 * J_;
    int c0 = tid >> 6;
    int m  = (tid & 63) * 4;
    float4 vb[16];
#pragma unroll
    for (int k = 0; k < 16; ++k) {
      size_t off = sbase + (size_t)(c0 + 4 * k) * PLANE + m;
      size_t offc = off > (size_t)(BCTJ - 4) ? (size_t)(BCTJ - 4) : off;
      float4 v = *(const float4*)(x + offc);
      if (off != offc) {           // clamped-by-2 edge: shift to real elements
        v.x = v.z; v.y = v.w; v.z = 0.f; v.w = 0.f;
      }
      vb[k] = v;
    }
#pragma unroll
    for (int k = 0; k < 16; ++k) {
      int c = c0 + 4 * k;
      unsigned p0 = (unsigned)f2h(vb[k].x) | ((unsigned)f2h(vb[k].y) << 16);
      unsigned p1 = (unsigned)f2h(vb[k].z) | ((unsigned)f2h(vb[k].w) << 16);
      int elem = ((c << 8) | m) ^ ((c & 7) << 3);
      *(uint2*)&Xs[elem] = make_uint2(p0, p1);
    }
  }
  __syncthreads();

  int l = tid & 63, w = tid >> 6;
  int lr = l & 15, lh = l >> 4;
  int n0 = w * 64;

  // ---- pass 1: XA = X * Ad ----
  f32x4 acc1[4][4];
#pragma unroll
  for (int mf = 0; mf < 4; ++mf)
#pragma unroll
    for (int nf = 0; nf < 4; ++nf) acc1[mf][nf] = (f32x4)0.f;

  int qminw = ((n0 / 25) * 25) >> 5;
  int qmaxw = min(7, ((((n0 + 63) / 25) + 1) * 25 - 1) >> 5);
  for (int q = qminw; q <= qmaxw; ++q) {
    f16x8 afx[4];
#pragma unroll
    for (int mf = 0; mf < 4; ++mf) {
      int c = mf * 16 + lr;
      int elem = ((c << 8) | (q * 32 + lh * 8)) ^ ((c & 7) << 3);
      afx[mf] = *(const f16x8*)&Xs[elem];
    }
#pragma unroll
    for (int nf = 0; nf < 4; ++nf) {
      int nbase = n0 + nf * 16;
      int ql = ((nbase / 25) * 25) >> 5;
      int qh = min(7, ((((nbase + 15) / 25) + 1) * 25 - 1) >> 5);
      if (q < ql || q > qh) continue;
      int n = nbase + lr;
      f16x8 bfx = *(const f16x8*)&AdT[n * 256 + q * 32 + lh * 8];
#pragma unroll
      for (int mf = 0; mf < 4; ++mf)
        acc1[mf][nf] = __builtin_amdgcn_mfma_f32_16x16x32_f16(afx[mf], bfx, acc1[mf][nf], 0, 0, 0);
    }
  }
  __syncthreads();

  // ---- write XA into same buffer, [n][c] swizzled ----
#pragma unroll
  for (int mf = 0; mf < 4; ++mf) {
    int cb = mf * 16 + 4 * lh;
#pragma unroll
    for (int nf = 0; nf < 4; ++nf) {
      int n = n0 + nf * 16 + lr;
      unsigned p0 = (unsigned)f2h(acc1[mf][nf][0]) | ((unsigned)f2h(acc1[mf][nf][1]) << 16);
      unsigned p1 = (unsigned)f2h(acc1[mf][nf][2]) | ((unsigned)f2h(acc1[mf][nf][3]) << 16);
      int e0 = ((n << 6) | cb) ^ ((n & 7) << 3);
      *(uint2*)&Xs[e0] = make_uint2(p0, p1);
    }
  }
  __syncthreads();

  // ---- pass 2: y1 = Gb * XA + bias ----
  f32x4 acc[4][4];
#pragma unroll
  for (int mf = 0; mf < 4; ++mf)
#pragma unroll
    for (int nf = 0; nf < 4; ++nf) acc[mf][nf] = (f32x4)0.f;

  f16x8 af[4][2];
#pragma unroll
  for (int mf = 0; mf < 4; ++mf) {
    const unsigned short* wp = Gb + (mf * 16 + lr) * C_ + lh * 8;
    af[mf][0] = *(const f16x8*)(wp);
    af[mf][1] = *(const f16x8*)(wp + 32);
  }
  f16x8 bfr[4][2];
#pragma unroll
  for (int nf = 0; nf < 4; ++nf) {
    int r = n0 + nf * 16 + lr;
    int sw = (r & 7) << 3;
    bfr[nf][0] = *(const f16x8*)&Xs[((r << 6) | (lh * 8)) ^ sw];
    bfr[nf][1] = *(const f16x8*)&Xs[((r << 6) | (32 + lh * 8)) ^ sw];
  }
#pragma unroll
  for (int mf = 0; mf < 4; ++mf)
#pragma unroll
    for (int nf = 0; nf < 4; ++nf) {
      acc[mf][nf] = __builtin_amdgcn_mfma_f32_16x16x32_f16(af[mf][0], bfr[nf][0], acc[mf][nf], 0, 0, 0);
      acc[mf][nf] = __builtin_amdgcn_mfma_f32_16x16x32_f16(af[mf][1], bfr[nf][1], acc[mf][nf], 0, 0, 0);
    }
  __syncthreads();

  // ---- epilogue: stats + f16 transpose into LDS [n][c] ----
#pragma unroll
  for (int mf = 0; mf < 4; ++mf) {
    float4 gb4 = *(const float4*)(gbias + mf * 16 + 4 * lh);
    int cb = mf * 16 + 4 * lh;
    float sv[4] = {0.f, 0.f, 0.f, 0.f}, qv[4] = {0.f, 0.f, 0.f, 0.f};
#pragma unroll
    for (int nf = 0; nf < 4; ++nf) {
      int n = n0 + nf * 16 + lr;
      float v0 = acc[mf][nf][0] + gb4.x;
      float v1 = acc[mf][nf][1] + gb4.y;
      float v2 = acc[mf][nf][2] + gb4.z;
      float v3 = acc[mf][nf][3] + gb4.w;
      if (n < 250) {
        sv[0] += v0; qv[0] += v0 * v0;
        sv[1] += v1; qv[1] += v1 * v1;
        sv[2] += v2; qv[2] += v2 * v2;
        sv[3] += v3; qv[3] += v3 * v3;
      }
      unsigned p0 = (unsigned)f2h(v0) | ((unsigned)f2h(v1) << 16);
      unsigned p1 = (unsigned)f2h(v2) | ((unsigned)f2h(v3) << 16);
      int e0 = ((n << 6) | cb) ^ ((n & 7) << 3);
      *(uint2*)&Xs[e0] = make_uint2(p0, p1);
    }
#pragma unroll
    for (int reg = 0; reg < 4; ++reg) {
      float s = sv[reg], q = qv[reg];
#pragma unroll
      for (int m = 1; m < 16; m <<= 1) {
        s += __shfl_xor(s, m);
        q += __shfl_xor(q, m);
      }
      if (lr == 0) {
        int o = mf * 16 + 4 * lh + reg;
        sred[w][o] = s; qred[w][o] = q;
      }
    }
  }
  __syncthreads();

  unsigned short* ydst = y1Tb + ((size_t)b * PLANE + (size_t)t0 * J_) * C_;
#pragma unroll
  for (int it = 0; it < 8; ++it) {
    int task = it * 256 + tid;
    int n = task >> 3, ch = task & 7;
    if (n < 250) {
      int e = ((n << 6) | (ch * 8)) ^ ((n & 7) << 3);
      u16x8 v = *(const u16x8*)&Xs[e];
      *(u16x8*)(ydst + (size_t)n * C_ + ch * 8) = v;
    }
  }
  if (tid < 64) {
    float S = 0.f, Q = 0.f;
#pragma unroll
    for (int i = 0; i < 4; ++i) { S += sred[i][tid]; Q += qred[i][tid]; }
    part1[bid * 128 + tid] = S;
    part1[bid * 128 + 64 + tid] = Q;
  }
}

// ---------------------------------------------------------------------------
// K3: grid-parallel reduce: one block per channel c (grid=64).
__global__ __launch_bounds__(256) void bnparam_reduce_kernel(
    const float* __restrict__ part, int nparts,
    const float* __restrict__ g, const float* __restrict__ b,
    float* __restrict__ bnp, unsigned short* __restrict__ bnph) {
  int c = blockIdx.x;
  int tid = threadIdx.x;
  float S = 0.f, Q = 0.f;
  for (int k = tid; k < nparts; k += 256) {
    S += part[k * 128 + c];
    Q += part[k * 128 + 64 + c];
  }
#pragma unroll
  for (int off = 32; off > 0; off >>= 1) {
    S += __shfl_down(S, off);
    Q += __shfl_down(Q, off);
  }
  __shared__ float ls[2][4];
  int wv = tid >> 6, ln = tid & 63;
  if (ln == 0) { ls[0][wv] = S; ls[1][wv] = Q; }
  __syncthreads();
  if (tid == 0) {
    float St = ls[0][0] + ls[0][1] + ls[0][2] + ls[0][3];
    float Qt = ls[1][0] + ls[1][1] + ls[1][2] + ls[1][3];
    float mean = St / BN_N;
    float var = Qt / BN_N - mean * mean;
    float inv = rsqrtf(var + BN_EPS);
    float sc = g[c] * inv;
    float sh = b[c] - mean * sc;
    bnp[c] = sc;
    bnp[C_ + c] = sh;
    bnph[c] = f2h(sc);
    bnph[C_ + c] = f2h(sh);
  }
}

// ---------------------------------------------------------------------------
// K4: TCN. DMA staging (pre-swizzled source); BN1+ReLU fused at B-frag read;
//     2-deep pipeline on both operands; s_setprio around MFMA cluster.
constexpr int TT = 10;
constexpr int ZROWS_TOT = 456;               // 450 DMA'd + 6 garbage (masked)
__global__ __launch_bounds__(256, 2) void tcn_mfma_kernel(
    const unsigned short* __restrict__ y1Tb, const unsigned short* __restrict__ Wb,
    const unsigned short* __restrict__ bnph1, const float* __restrict__ tbias,
    unsigned short* __restrict__ y2b, float* __restrict__ part2) {
  __shared__ unsigned short zs[ZROWS_TOT * C_];   // 58368 B; reused as [o][260]
  __shared__ float sred[4][64], qred[4][64];      // 2 KB
  unsigned short* zs2 = zs;                       // alias (33.3 KB)
  int bid = (blockIdx.x & 7) * 120 + (blockIdx.x >> 3);   // match gcn mapping
  int b = bid / (T_ / TT), tile = bid % (T_ / TT);
  int t0 = tile * TT;
  int tid = threadIdx.x;
  int g0 = t0 * J_ - 100;                          // global row of zs row 0

  // ---- phase 1: async DMA of 450 raw rows, source pre-swizzled per lane ----
  {
    const unsigned short* bb = y1Tb + (size_t)b * PLANE * C_;
#pragma unroll
    for (int k = 0; k < 15; ++k) {
      int P = k * 256 + tid;                       // linear granule position
      if (P < 3600) {
        int r = P >> 3, p = P & 7;
        int gr = g0 + r;
        int grc = min(max(gr, 0), PLANE - 1);      // clamp (masked in phase 3)
        const unsigned short* src = bb + (size_t)grc * C_ + ((p ^ (r & 7)) << 3);
        int ldsoff = (k * 256 + (tid & 192)) << 4; // wave-uniform byte base
        gload16(src, (unsigned short*)((char*)zs + ldsoff));
      }
    }
  }

  int l = tid & 63, w = tid >> 6;
  int lr = l & 15, lh = l >> 4;
  int n0 = w * 64;

  // per-lane BN params for c-octets [lh*8, +8) and [32+lh*8, +8)
  f16x2 scA[4], shA[4], scB[4], shB[4];
  {
    const f16x2* scp = (const f16x2*)(bnph1);
    const f16x2* shp = (const f16x2*)(bnph1 + C_);
#pragma unroll
    for (int i = 0; i < 4; ++i) {
      scA[i] = scp[lh * 4 + i];      shA[i] = shp[lh * 4 + i];
      scB[i] = scp[16 + lh * 4 + i]; shB[i] = shp[16 + lh * 4 + i];
    }
  }
  f16x2 z2 = (f16x2)((_Float16)0.f);

  f32x4 acc[4][4];
#pragma unroll
  for (int mf = 0; mf < 4; ++mf)
#pragma unroll
    for (int nf = 0; nf < 4; ++nf) acc[mf][nf] = (f32x4)0.f;

  // weight prefetch for kt=0 (overlaps DMA drain)
  f16x8 afc[4][2];
#pragma unroll
  for (int mf = 0; mf < 4; ++mf) {
    const unsigned short* wp = Wb + (mf * 16 + lr) * C_ + lh * 8;
    afc[mf][0] = *(const f16x8*)(wp);
    afc[mf][1] = *(const f16x8*)(wp + 32);
  }
  __syncthreads();   // drains DMA vmcnt before LDS reads

  // B-frag loader (raw LDS reads -> BN -> mask), as a lambda
  auto load_bfr = [&](int kt, f16x8 out[4][2]) {
#pragma unroll
    for (int nf = 0; nf < 4; ++nf) {
      int r = n0 + nf * 16 + lr + 25 * kt;
      int gr = g0 + r;
      int sw = (r & 7) << 3;
      uint4 ra = *(const uint4*)&zs[((r << 6) | (lh * 8)) ^ sw];
      uint4 rb = *(const uint4*)&zs[((r << 6) | (32 + lh * 8)) ^ sw];
      f16x2 a0 = __builtin_bit_cast(f16x2, ra.x);
      f16x2 a1 = __builtin_bit_cast(f16x2, ra.y);
      f16x2 a2 = __builtin_bit_cast(f16x2, ra.z);
      f16x2 a3 = __builtin_bit_cast(f16x2, ra.w);
      f16x2 b0 = __builtin_bit_cast(f16x2, rb.x);
      f16x2 b1 = __builtin_bit_cast(f16x2, rb.y);
      f16x2 b2 = __builtin_bit_cast(f16x2, rb.z);
      f16x2 b3 = __builtin_bit_cast(f16x2, rb.w);
      a0 = __builtin_elementwise_max(a0 * scA[0] + shA[0], z2);
      a1 = __builtin_elementwise_max(a1 * scA[1] + shA[1], z2);
      a2 = __builtin_elementwise_max(a2 * scA[2] + shA[2], z2);
      a3 = __builtin_elementwise_max(a3 * scA[3] + shA[3], z2);
      b0 = __builtin_elementwise_max(b0 * scB[0] + shB[0], z2);
      b1 = __builtin_elementwise_max(b1 * scB[1] + shB[1], z2);
      b2 = __builtin_elementwise_max(b2 * scB[2] + shB[2], z2);
      b3 = __builtin_elementwise_max(b3 * scB[3] + shB[3], z2);
      unsigned m = ((unsigned)gr < (unsigned)PLANE && r < 450) ? 0xFFFFFFFFu : 0u;
      uint4 pa, pb;
      pa.x = __builtin_bit_cast(unsigned int, a0) & m;
      pa.y = __builtin_bit_cast(unsigned int, a1) & m;
      pa.z = __builtin_bit_cast(unsigned int, a2) & m;
      pa.w = __builtin_bit_cast(unsigned int, a3) & m;
      pb.x = __builtin_bit_cast(unsigned int, b0) & m;
      pb.y = __builtin_bit_cast(unsigned int, b1) & m;
      pb.z = __builtin_bit_cast(unsigned int, b2) & m;
      pb.w = __builtin_bit_cast(unsigned int, b3) & m;
      out[nf][0] = __builtin_bit_cast(f16x8, pa);
      out[nf][1] = __builtin_bit_cast(f16x8, pb);
    }
  };

  f16x8 bcur[4][2], bnxt[4][2];
  load_bfr(0, bcur);

#pragma unroll
  for (int kt = 0; kt < K9; ++kt) {
    f16x8 afn[4][2];
    if (kt < K9 - 1) {
#pragma unroll
      for (int mf = 0; mf < 4; ++mf) {
        const unsigned short* wp = Wb + (kt + 1) * (C_ * C_) + (mf * 16 + lr) * C_ + lh * 8;
        afn[mf][0] = *(const f16x8*)(wp);
        afn[mf][1] = *(const f16x8*)(wp + 32);
      }
      load_bfr(kt + 1, bnxt);
    }
    __builtin_amdgcn_s_setprio(1);
#pragma unroll
    for (int mf = 0; mf < 4; ++mf)
#pragma unroll
      for (int nf = 0; nf < 4; ++nf) {
        acc[mf][nf] = __builtin_amdgcn_mfma_f32_16x16x32_f16(afc[mf][0], bcur[nf][0], acc[mf][nf], 0, 0, 0);
        acc[mf][nf] = __builtin_amdgcn_mfma_f32_16x16x32_f16(afc[mf][1], bcur[nf][1], acc[mf][nf], 0, 0, 0);
      }
    __builtin_amdgcn_s_setprio(0);
    if (kt < K9 - 1) {
#pragma unroll
      for (int mf = 0; mf < 4; ++mf) {
        afc[mf][0] = afn[mf][0];
        afc[mf][1] = afn[mf][1];
      }
#pragma unroll
      for (int nf = 0; nf < 4; ++nf) {
        bcur[nf][0] = bnxt[nf][0];
        bcur[nf][1] = bnxt[nf][1];
      }
    }
  }
  __syncthreads();   // done reading zs before zs2 overwrite

  // ---- epilogue: stats + f16 transpose into LDS [o][260] ----
#pragma unroll
  for (int mf = 0; mf < 4; ++mf) {
    float4 tb4 = *(const float4*)(tbias + mf * 16 + 4 * lh);
    float sv[4] = {0.f, 0.f, 0.f, 0.f}, qv[4] = {0.f, 0.f, 0.f, 0.f};
#pragma unroll
    for (int nf = 0; nf < 4; ++nf) {
      int n = n0 + nf * 16 + lr;
      if (n < 250) {
#pragma unroll
        for (int reg = 0; reg < 4; ++reg) {
          int o = mf * 16 + 4 * lh + reg;
          float v = acc[mf][nf][reg] + ((const float*)&tb4)[reg];
          zs2[o * 260 + n] = f2h(v);
          sv[reg] += v; qv[reg] += v * v;
        }
      }
    }
#pragma unroll
    for (int reg = 0; reg < 4; ++reg) {
      float s = sv[reg], q = qv[reg];
#pragma unroll
      for (int m = 1; m < 16; m <<= 1) {
        s += __shfl_xor(s, m);
        q += __shfl_xor(q, m);
      }
      if (lr == 0) {
        int o = mf * 16 + 4 * lh + reg;
        sred[w][o] = s; qred[w][o] = q;
      }
    }
  }
  __syncthreads();

  // ---- coalesced store: dword granularity, [o][plane] ----
  unsigned short* ydst = y2b + (size_t)b * (C_ * PLANE) + (size_t)t0 * J_;
#pragma unroll
  for (int it = 0; it < 32; ++it) {
    int task = it * 256 + tid;
    if (task < 8000) {
      int o = task / 125;
      int k = task - o * 125;
      unsigned d = *(const unsigned*)&zs2[o * 260 + 2 * k];
      *(unsigned*)(ydst + (size_t)o * PLANE + 2 * k) = d;
    }
  }
  if (tid < 64) {
    float S = 0.f, Q = 0.f;
#pragma unroll
    for (int i = 0; i < 4; ++i) { S += sred[i][tid]; Q += qred[i][tid]; }
    part2[bid * 128 + tid] = S;
    part2[bid * 128 + 64 + tid] = Q;
  }
}

// ---------------------------------------------------------------------------
// K5: out = relu(bn2(y2) + x); y2 f16 [b][c][plane], out f32.
__global__ __launch_bounds__(256) void final_kernel(const unsigned short* __restrict__ y2b,
                                                    const float* __restrict__ x,
                                                    const float* __restrict__ bnp2,
                                                    float* __restrict__ out) {
  int lb = (blockIdx.x & 7) * 1875 + (blockIdx.x >> 3);
  int i = lb * 256 + threadIdx.x;
  if (i >= BCTJ / 4) return;
  int c = (i / (PLANE / 4)) & (C_ - 1);
  float sc = bnp2[c], sh = bnp2[C_ + c];
  u16x4 yv = *(const u16x4*)(y2b + (size_t)i * 4);
  float4 xv = ((const float4*)x)[i];
  float4 v;
  v.x = fmaxf(fmaf(h2f(yv[0]), sc, sh) + xv.x, 0.f);
  v.y = fmaxf(fmaf(h2f(yv[1]), sc, sh) + xv.y, 0.f);
  v.z = fmaxf(fmaf(h2f(yv[2]), sc, sh) + xv.z, 0.f);
  v.w = fmaxf(fmaf(h2f(yv[3]), sc, sh) + xv.w, 0.f);
  ((float4*)out)[i] = v;
}

// ---------------------------------------------------------------------------
extern "C" void kernel_launch(void* const* d_in, const int* in_sizes, int n_in,
                              void* d_out, int out_size, void* d_ws, size_t ws_size,
                              hipStream_t stream) {
  const float* x     = (const float*)d_in[0];
  const float* A     = (const float*)d_in[1];
  const float* gcn_w = (const float*)d_in[2];
  const float* gcn_b = (const float*)d_in[3];
  const float* bn1_g = (const float*)d_in[4];
  const float* bn1_b = (const float*)d_in[5];
  const float* tcn_w = (const float*)d_in[6];
  const float* tcn_b = (const float*)d_in[7];
  const float* bn2_g = (const float*)d_in[8];
  const float* bn2_b = (const float*)d_in[9];
  float* out = (float*)d_out;

  unsigned short* y1Tb = (unsigned short*)d_ws;           // BCTJ f16
  unsigned short* y2b  = y1Tb + BCTJ;                     // BCTJ f16
  unsigned short* Wb   = y2b + BCTJ;                      // 36,864 f16
  unsigned short* Gb   = Wb + C_ * C_ * K9;               // 4,096 f16
  unsigned short* AdT  = Gb + C_ * C_;                    // 65,536 f16
  unsigned short* bnph = AdT + 256 * 256;                 // 256 f16 (bn1h, bn2h)
  float* part = (float*)(bnph + 256);                     // 960*128 f32
  float* bnp  = part + 960 * 128;                         // 256 f32

  int prep_n = C_ * C_ * K9 + C_ * C_ + 256 * 256;
  prep_kernel<<<(prep_n + 255) / 256, 256, 0, stream>>>(tcn_w, gcn_w, A, Wb, Gb, AdT);
  gcn_mfma_kernel<<<B_ * (T_ / TTG), 256, 0, stream>>>(x, AdT, Gb, gcn_b, y1Tb, part);
  bnparam_reduce_kernel<<<64, 256, 0, stream>>>(part, B_ * (T_ / TTG), bn1_g, bn1_b, bnp, bnph);
  tcn_mfma_kernel<<<B_ * (T_ / TT), 256, 0, stream>>>(y1Tb, Wb, bnph, tcn_b, y2b, part);
  bnparam_reduce_kernel<<<64, 256, 0, stream>>>(part, B_ * (T_ / TT), bn2_g, bn2_b, bnp + 128, bnph + 128);
  final_kernel<<<BCTJ / 4 / 256, 256, 0, stream>>>(y2b, x, bnp + 128, out);
}